// Round 1
// baseline (221.430 us; speedup 1.0000x reference)
//
#include <hip/hip_runtime.h>
#include <hip/hip_bf16.h>

#define AS 20      // alphabet size
#define ASS 400    // AS*AS
#define KK 8       // rate matrices
#define BB 256
#define MM 2
#define LL 1024

__device__ __forceinline__ float softplus_f(float x) {
    return x > 20.f ? x : log1pf(expf(x));
}

// One block (64 threads) per (m,b,k): build Q -> Ssym, expm via scale&square,
// write P = diag(1/sqrt p) * expm(tau*Ssym) * diag(sqrt p) to workspace.
__global__ __launch_bounds__(64) void build_P(
    const float* __restrict__ exch,   // (m,k,20,20)
    const float* __restrict__ eqk,    // (m,k,20)
    const float* __restrict__ tauk,   // (m,b)
    const float* __restrict__ pmr,    // (m,k)
    float* __restrict__ Pout)         // (m,b,k,20,20)
{
    const int mbk = blockIdx.x;
    const int ki = mbk % KK;
    const int bi = (mbk / KK) % BB;
    const int mi = mbk / (KK * BB);
    const int t = threadIdx.x;

    __shared__ float p[AS], sp[AS], isp[AS], rowsum[AS];
    __shared__ float A[ASS], Bm[ASS], Cm[ASS];
    __shared__ float scal[2];
    __shared__ int s_sh;

    const float* Km = exch + (size_t)(mi * KK + ki) * ASS;
    const float* ev = eqk + (size_t)(mi * KK + ki) * AS;

    if (t == 0) {
        float mx = -1e30f;
        for (int i = 0; i < AS; i++) mx = fmaxf(mx, ev[i]);
        float sum = 0.f;
        for (int i = 0; i < AS; i++) { float e = expf(ev[i] - mx); p[i] = e; sum += e; }
        for (int i = 0; i < AS; i++) {
            p[i] /= sum;
            sp[i] = sqrtf(p[i]);
            isp[i] = 1.0f / sp[i];
        }
        scal[0] = softplus_f(tauk[mi * BB + bi]) * softplus_f(pmr[mi * KK + ki]);
    }
    __syncthreads();

    // Q0 = softplus(sym(K)) * (1-eye) * p_j   -> A
    for (int f = t; f < ASS; f += 64) {
        int i = f / AS, j = f % AS;
        float Kv = 0.5f * (Km[i * AS + j] + Km[j * AS + i]);
        float Rv = (i == j) ? 0.f : softplus_f(Kv);
        A[f] = Rv * p[j];
    }
    __syncthreads();
    if (t < AS) {
        float r = 0.f;
        for (int j = 0; j < AS; j++) r += A[t * AS + j];
        rowsum[t] = r;
    }
    __syncthreads();
    if (t == 0) {
        float mue = 0.f;
        for (int i = 0; i < AS; i++) mue += p[i] * rowsum[i];
        scal[1] = 1.0f / fmaxf(mue, 1e-16f);
    }
    __syncthreads();

    const float tau = scal[0], inv_mue = scal[1];
    // raw Ssym -> Bm
    for (int f = t; f < ASS; f += 64) {
        int i = f / AS, j = f % AS;
        float Qv = (A[f] - (i == j ? rowsum[i] : 0.f)) * inv_mue;
        Bm[f] = sp[i] * Qv * isp[j];
    }
    __syncthreads();
    // X = tau * 0.5*(Ssym + Ssym^T) -> A
    for (int f = t; f < ASS; f += 64) {
        int i = f / AS, j = f % AS;
        A[f] = tau * 0.5f * (Bm[f] + Bm[j * AS + i]);
    }
    __syncthreads();
    // inf-norm -> scaling count
    if (t < AS) {
        float r = 0.f;
        for (int j = 0; j < AS; j++) r += fabsf(A[t * AS + j]);
        rowsum[t] = r;
    }
    __syncthreads();
    if (t == 0) {
        float nrm = 0.f;
        for (int i = 0; i < AS; i++) nrm = fmaxf(nrm, rowsum[i]);
        int s = 0;
        if (nrm > 0.5f) {
            s = (int)ceilf(log2f(nrm * 2.0f));
            if (s < 0) s = 0;
            if (s > 30) s = 30;
        }
        s_sh = s;
    }
    __syncthreads();
    const int sq = s_sh;
    const float sc = ldexpf(1.0f, -sq);
    for (int f = t; f < ASS; f += 64) A[f] *= sc;   // T
    for (int f = t; f < ASS; f += 64) Bm[f] = (f / AS == f % AS) ? 1.0f : 0.0f;
    __syncthreads();

    // Horner Taylor: E = I + T*(I + T/2*(I + ... ))
    for (int n = 10; n >= 1; --n) {
        const float invn = 1.0f / (float)n;
        for (int f = t; f < ASS; f += 64) {
            int i = f / AS, j = f % AS;
            float acc = 0.f;
            #pragma unroll
            for (int z = 0; z < AS; z++) acc += A[i * AS + z] * Bm[z * AS + j];
            Cm[f] = (i == j ? 1.0f : 0.0f) + acc * invn;
        }
        __syncthreads();
        for (int f = t; f < ASS; f += 64) Bm[f] = Cm[f];
        __syncthreads();
    }
    // squarings
    for (int q = 0; q < sq; q++) {
        for (int f = t; f < ASS; f += 64) {
            int i = f / AS, j = f % AS;
            float acc = 0.f;
            #pragma unroll
            for (int z = 0; z < AS; z++) acc += Bm[i * AS + z] * Bm[z * AS + j];
            Cm[f] = acc;
        }
        __syncthreads();
        for (int f = t; f < ASS; f += 64) Bm[f] = Cm[f];
        __syncthreads();
    }
    // P = diag(isp) * E * diag(sp)
    float* Po = Pout + (size_t)mbk * ASS;
    for (int f = t; f < ASS; f += 64) {
        int i = f / AS, j = f % AS;
        Po[f] = isp[i] * Bm[f] * sp[j];
    }
}

// out[mb,l,ki,s] = sum_z seq[mb,l,z] * P[mb,ki,z,s]
// grid: (m*b*2) blocks; block handles one (m,b) and half of L. 320 threads:
// j = t%160 -> (ki,s) output column (P column in regs); sub = t/160 row split.
__global__ __launch_bounds__(320) void apply_P(
    const float* __restrict__ seq,   // (m,b,L,20)
    const float* __restrict__ Pws,   // (m,b,k,20,20)
    float* __restrict__ out)         // (m,b,L,k,20)
{
    const int blk = blockIdx.x;
    const int mb = blk >> 1;
    const int half = blk & 1;
    const int t = threadIdx.x;
    const int j = t % 160;       // ki*20 + s
    const int sub = t / 160;     // 0 or 1
    const int ki = j / AS, s = j % AS;

    float Preg[AS];
    const float* Pm = Pws + (size_t)(mb * KK + ki) * ASS;
    #pragma unroll
    for (int z = 0; z < AS; z++) Preg[z] = Pm[z * AS + s];

    __shared__ float sq_lds[64 * AS];
    const int rowbase = half * (LL / 2);
    const float* seqb = seq + (size_t)mb * LL * AS;
    float* outb = out + (size_t)mb * LL * 160;

    for (int c = 0; c < 8; c++) {
        const int l0 = rowbase + c * 64;
        for (int idx = t; idx < 64 * AS; idx += 320)
            sq_lds[idx] = seqb[(size_t)l0 * AS + idx];
        __syncthreads();
        const int lr0 = sub * 32;
        for (int lr = lr0; lr < lr0 + 32; ++lr) {
            const float4* rp = reinterpret_cast<const float4*>(&sq_lds[lr * AS]);
            float acc = 0.f;
            #pragma unroll
            for (int q = 0; q < 5; q++) {
                float4 v = rp[q];
                acc = fmaf(v.x, Preg[4 * q + 0], acc);
                acc = fmaf(v.y, Preg[4 * q + 1], acc);
                acc = fmaf(v.z, Preg[4 * q + 2], acc);
                acc = fmaf(v.w, Preg[4 * q + 3], acc);
            }
            outb[(size_t)(l0 + lr) * 160 + j] = acc;
        }
        __syncthreads();
    }
}

extern "C" void kernel_launch(void* const* d_in, const int* in_sizes, int n_in,
                              void* d_out, int out_size, void* d_ws, size_t ws_size,
                              hipStream_t stream) {
    const float* seq  = (const float*)d_in[0];
    const float* exch = (const float*)d_in[1];
    const float* eqk  = (const float*)d_in[2];
    const float* tauk = (const float*)d_in[3];
    const float* pmr  = (const float*)d_in[4];
    float* out = (float*)d_out;
    float* Pws = (float*)d_ws;   // needs m*b*k*400*4 = 6.55 MB

    hipLaunchKernelGGL(build_P, dim3(MM * BB * KK), dim3(64), 0, stream,
                       exch, eqk, tauk, pmr, Pws);
    hipLaunchKernelGGL(apply_P, dim3(MM * BB * 2), dim3(320), 0, stream,
                       seq, Pws, out);
}

// Round 3
// 136.117 us; speedup vs baseline: 1.6268x; 1.6268x over previous
//
#include <hip/hip_runtime.h>

#define AS 20      // alphabet size
#define ASS 400    // AS*AS
#define KK 8
#define BB 256
#define MM 2
#define LL 1024

__device__ __forceinline__ float softplus_f(float x) {
    return x > 20.f ? x : log1pf(expf(x));
}

// ---- 20x20 matmul C = A*B in LDS, 2x4 register-tiled, threads 0..49 ----
__device__ __forceinline__ void mul20(const float* __restrict__ A,
                                      const float* __restrict__ B,
                                      float* __restrict__ C, int t) {
    if (t < 50) {
        const int i2 = (t / 5) * 2;
        const int c4 = (t % 5) * 4;
        float a0[AS], a1[AS];
        #pragma unroll
        for (int q = 0; q < 5; q++) {
            float4 v0 = *(const float4*)&A[i2 * AS + 4 * q];
            float4 v1 = *(const float4*)&A[(i2 + 1) * AS + 4 * q];
            a0[4*q] = v0.x; a0[4*q+1] = v0.y; a0[4*q+2] = v0.z; a0[4*q+3] = v0.w;
            a1[4*q] = v1.x; a1[4*q+1] = v1.y; a1[4*q+2] = v1.z; a1[4*q+3] = v1.w;
        }
        float4 s0 = {0.f,0.f,0.f,0.f}, s1 = {0.f,0.f,0.f,0.f};
        #pragma unroll
        for (int z = 0; z < AS; z++) {
            float4 bv = *(const float4*)&B[z * AS + c4];
            s0.x = fmaf(a0[z], bv.x, s0.x); s0.y = fmaf(a0[z], bv.y, s0.y);
            s0.z = fmaf(a0[z], bv.z, s0.z); s0.w = fmaf(a0[z], bv.w, s0.w);
            s1.x = fmaf(a1[z], bv.x, s1.x); s1.y = fmaf(a1[z], bv.y, s1.y);
            s1.z = fmaf(a1[z], bv.z, s1.z); s1.w = fmaf(a1[z], bv.w, s1.w);
        }
        *(float4*)&C[i2 * AS + c4] = s0;
        *(float4*)&C[(i2 + 1) * AS + c4] = s1;
    }
    __syncthreads();
}

// ---------- prep: per (m,k) build Ssym, sp, isp, rho, infnorm ----------
__global__ __launch_bounds__(64) void prep_S(
    const float* __restrict__ exch, const float* __restrict__ eqk,
    const float* __restrict__ pmr,
    float* __restrict__ Ssym_g, float* __restrict__ sp_g,
    float* __restrict__ isp_g, float* __restrict__ rho_g,
    float* __restrict__ nrm_g)
{
    const int mk = blockIdx.x;
    const int t = threadIdx.x;
    __shared__ float p[AS], sp[AS], isp[AS], rowsum[AS];
    __shared__ float A[ASS], S[ASS];
    __shared__ float inv_mue_sh;

    const float* Km = exch + (size_t)mk * ASS;
    const float* ev = eqk + (size_t)mk * AS;

    if (t == 0) {
        float mx = -1e30f;
        for (int i = 0; i < AS; i++) mx = fmaxf(mx, ev[i]);
        float sum = 0.f;
        for (int i = 0; i < AS; i++) { float e = expf(ev[i] - mx); p[i] = e; sum += e; }
        for (int i = 0; i < AS; i++) {
            p[i] /= sum;
            sp[i] = sqrtf(p[i]);
            isp[i] = 1.0f / sp[i];
        }
        rho_g[mk] = softplus_f(pmr[mk]);
    }
    __syncthreads();
    for (int f = t; f < ASS; f += 64) {
        int i = f / AS, j = f % AS;
        float Kv = 0.5f * (Km[i * AS + j] + Km[j * AS + i]);
        float Rv = (i == j) ? 0.f : softplus_f(Kv);
        A[f] = Rv * p[j];
    }
    __syncthreads();
    if (t < AS) {
        float r = 0.f;
        for (int j = 0; j < AS; j++) r += A[t * AS + j];
        rowsum[t] = r;
    }
    __syncthreads();
    if (t == 0) {
        float mue = 0.f;
        for (int i = 0; i < AS; i++) mue += p[i] * rowsum[i];
        inv_mue_sh = 1.0f / fmaxf(mue, 1e-16f);
    }
    __syncthreads();
    for (int f = t; f < ASS; f += 64) {
        int i = f / AS, j = f % AS;
        float Qv = (A[f] - (i == j ? rowsum[i] : 0.f)) * inv_mue_sh;
        S[f] = sp[i] * Qv * isp[j];
    }
    __syncthreads();
    for (int f = t; f < ASS; f += 64) {
        int i = f / AS, j = f % AS;
        float v = 0.5f * (S[f] + S[j * AS + i]);
        A[f] = v;
        Ssym_g[(size_t)mk * ASS + f] = v;
    }
    __syncthreads();
    if (t < AS) {
        float r = 0.f;
        for (int j = 0; j < AS; j++) r += fabsf(A[t * AS + j]);
        rowsum[t] = r;
    }
    __syncthreads();
    if (t == 0) {
        float n = 0.f;
        for (int i = 0; i < AS; i++) n = fmaxf(n, rowsum[i]);
        nrm_g[mk] = n;
    }
    if (t < AS) { sp_g[mk * AS + t] = sp[t]; isp_g[mk * AS + t] = isp[t]; }
}

// ---------- expm per (m,b,k): Paterson-Stockmeyer deg-9 + squaring ----------
__global__ __launch_bounds__(64) void expm_P(
    const float* __restrict__ Ssym_g, const float* __restrict__ sp_g,
    const float* __restrict__ isp_g, const float* __restrict__ rho_g,
    const float* __restrict__ nrm_g, const float* __restrict__ tauk,
    float* __restrict__ Pout)
{
    const int mbk = blockIdx.x;
    const int ki = mbk % KK;
    const int bi = (mbk / KK) % BB;
    const int mi = mbk / (KK * BB);
    const int mk = mi * KK + ki;
    const int t = threadIdx.x;

    __shared__ float T[ASS], T2[ASS], T3[ASS], Xa[ASS], Xb[ASS];

    const float tau = softplus_f(tauk[mi * BB + bi]) * rho_g[mk];
    const float nt = tau * nrm_g[mk];
    int s = 0;
    if (nt > 1.0f) {
        s = (int)ceilf(log2f(nt));
        if (s < 0) s = 0;
        if (s > 30) s = 30;
    }
    const float sc = ldexpf(tau, -s);

    for (int f = t; f < ASS; f += 64) T[f] = sc * Ssym_g[(size_t)mk * ASS + f];
    __syncthreads();
    mul20(T, T, T2, t);
    mul20(T2, T, T3, t);

    const float C2 = 0.5f, C3 = 1.f/6.f, C4 = 1.f/24.f, C5 = 1.f/120.f,
                C6 = 1.f/720.f, C7 = 1.f/5040.f, C8 = 1.f/40320.f, C9 = 1.f/362880.f;

    // Xa = c6 I + c7 T + c8 T2 + c9 T3
    for (int f = t; f < ASS; f += 64) {
        int i = f / AS, j = f % AS;
        Xa[f] = ((i == j) ? C6 : 0.f) + C7 * T[f] + C8 * T2[f] + C9 * T3[f];
    }
    __syncthreads();
    mul20(T3, Xa, Xb, t);
    // Xa = B1 + Xb
    for (int f = t; f < ASS; f += 64) {
        int i = f / AS, j = f % AS;
        Xa[f] = ((i == j) ? C3 : 0.f) + C4 * T[f] + C5 * T2[f] + Xb[f];
    }
    __syncthreads();
    mul20(T3, Xa, Xb, t);
    // Xa = I + T + 0.5 T2 + Xb
    for (int f = t; f < ASS; f += 64) {
        int i = f / AS, j = f % AS;
        Xa[f] = ((i == j) ? 1.f : 0.f) + T[f] + C2 * T2[f] + Xb[f];
    }
    __syncthreads();
    for (int q = 0; q < s; q++) {
        if ((q & 1) == 0) mul20(Xa, Xa, Xb, t);
        else              mul20(Xb, Xb, Xa, t);
    }

    float* Po = Pout + (size_t)mbk * ASS;
    const float* E = (s & 1) ? Xb : Xa;
    for (int f = t; f < ASS; f += 64) {
        int i = f / AS, j = f % AS;
        Po[f] = isp_g[mk * AS + i] * E[f] * sp_g[mk * AS + j];
    }
}

// ---------- apply: out[mb,l,c] = sum_z seq[mb,l,z] * P[mb,c/20,z,c%20] ----------
// 1024 blocks (mb, half), 320 threads: j=t%40 owns 4 contiguous cols, rg=t/40 rows.
__global__ __launch_bounds__(320, 4) void apply_P(
    const float* __restrict__ seq, const float* __restrict__ Pws,
    float* __restrict__ out)
{
    const int blk = blockIdx.x;
    const int mb = blk >> 1;
    const int half = blk & 1;
    const int t = threadIdx.x;
    const int j = t % 40;        // column group: cols 4j..4j+3
    const int rg = t / 40;       // row group 0..7
    const int ki = j / 5;        // 4j/20
    const int s0 = (j % 5) * 4;  // 4j%20

    float4 Preg[AS];
    const float* Pm = Pws + (size_t)(mb * KK + ki) * ASS + s0;
    #pragma unroll
    for (int z = 0; z < AS; z++) Preg[z] = *(const float4*)(Pm + z * AS);

    // one chunk = 64 rows x 20 floats = 1280 floats = 320 float4 (1 per thread)
    __shared__ float4 sbuf[2][320];
    const int rowbase = half * (LL / 2);
    const float* seqb = seq + (size_t)mb * LL * AS;
    float* outb = out + (size_t)mb * LL * (KK * AS);

    // prologue: stage chunk 0
    {
        const float4* g = (const float4*)(seqb + (size_t)rowbase * AS);
        sbuf[0][t] = g[t];
    }
    __syncthreads();

    for (int c = 0; c < 8; c++) {
        const int cur = c & 1;
        float4 rnext;
        if (c < 7) {  // early-issue next chunk's global load
            const float4* g = (const float4*)(seqb + (size_t)(rowbase + (c + 1) * 64) * AS);
            rnext = g[t];
        }
        const int l0 = rowbase + c * 64;
        #pragma unroll
        for (int rr = 0; rr < 8; rr++) {
            const int lr = rg * 8 + rr;
            const float4* row = &sbuf[cur][lr * 5];
            float4 acc = {0.f, 0.f, 0.f, 0.f};
            #pragma unroll
            for (int q = 0; q < 5; q++) {
                float4 sv = row[q];
                acc.x = fmaf(sv.x, Preg[4*q+0].x, acc.x); acc.y = fmaf(sv.x, Preg[4*q+0].y, acc.y);
                acc.z = fmaf(sv.x, Preg[4*q+0].z, acc.z); acc.w = fmaf(sv.x, Preg[4*q+0].w, acc.w);
                acc.x = fmaf(sv.y, Preg[4*q+1].x, acc.x); acc.y = fmaf(sv.y, Preg[4*q+1].y, acc.y);
                acc.z = fmaf(sv.y, Preg[4*q+1].z, acc.z); acc.w = fmaf(sv.y, Preg[4*q+1].w, acc.w);
                acc.x = fmaf(sv.z, Preg[4*q+2].x, acc.x); acc.y = fmaf(sv.z, Preg[4*q+2].y, acc.y);
                acc.z = fmaf(sv.z, Preg[4*q+2].z, acc.z); acc.w = fmaf(sv.z, Preg[4*q+2].w, acc.w);
                acc.x = fmaf(sv.w, Preg[4*q+3].x, acc.x); acc.y = fmaf(sv.w, Preg[4*q+3].y, acc.y);
                acc.z = fmaf(sv.w, Preg[4*q+3].z, acc.z); acc.w = fmaf(sv.w, Preg[4*q+3].w, acc.w);
            }
            *(float4*)&outb[(size_t)(l0 + lr) * 160 + 4 * j] = acc;
        }
        if (c < 7) sbuf[cur ^ 1][t] = rnext;
        __syncthreads();
    }
}

extern "C" void kernel_launch(void* const* d_in, const int* in_sizes, int n_in,
                              void* d_out, int out_size, void* d_ws, size_t ws_size,
                              hipStream_t stream) {
    const float* seq  = (const float*)d_in[0];
    const float* exch = (const float*)d_in[1];
    const float* eqk  = (const float*)d_in[2];
    const float* tauk = (const float*)d_in[3];
    const float* pmr  = (const float*)d_in[4];
    float* out = (float*)d_out;

    float* ws   = (float*)d_ws;
    float* Pws  = ws;                        // 4096*400 floats = 6.55 MB
    float* Ssym = ws + (size_t)MM*BB*KK*ASS; // 16*400
    float* spg  = Ssym + MM*KK*ASS;          // 16*20
    float* ispg = spg + MM*KK*AS;            // 16*20
    float* rhog = ispg + MM*KK*AS;           // 16
    float* nrmg = rhog + MM*KK;              // 16

    prep_S<<<dim3(MM * KK), dim3(64), 0, stream>>>(exch, eqk, pmr, Ssym, spg, ispg, rhog, nrmg);
    expm_P<<<dim3(MM * BB * KK), dim3(64), 0, stream>>>(Ssym, spg, ispg, rhog, nrmg, tauk, Pws);
    apply_P<<<dim3(MM * BB * 2), dim3(320), 0, stream>>>(seq, Pws, out);
}